// Round 4
// baseline (6522.564 us; speedup 1.0000x reference)
//
#include <hip/hip_runtime.h>
#include <hip/hip_bf16.h>

// CausalSelfAttention: B=4, N=2048, D=1024, H=16, HD=64
// fp32 in / fp32 out. Internals bf16 (kqv 50.3MB + sa 16.8MB = 64 MiB ws).
// R4: (1) GEMMs moved to bf16 MFMA (16x16x32), fragment-slot LDS layout;
//     (2) attn: 4 waves share one 64-query tile, keys split mod 4, merged at end
//         (occupancy 1 wave/SIMD -> 2/SIMD, balanced causal work).

#define NSEQ 2048
#define NHEAD 16
#define DMODEL 1024
#define KQV_COLS 3072

typedef unsigned short ushort_t;
typedef __attribute__((ext_vector_type(8))) short v8s;  // 8 bf16 = 4 VGPRs
typedef __attribute__((ext_vector_type(4))) float v4f;  // MFMA acc

__device__ __forceinline__ float bf2f(unsigned short u) {
    union { unsigned int i; float f; } v;
    v.i = ((unsigned int)u) << 16;
    return v.f;
}
__device__ __forceinline__ unsigned short f2bf(float f) {  // RNE (epilogue)
    unsigned int x = __float_as_uint(f);
    unsigned int r = x + 0x7fffu + ((x >> 16) & 1u);
    return (unsigned short)(r >> 16);
}
__device__ __forceinline__ unsigned short f2bf_rh(float f) {  // round-half-up, 2 ops (staging)
    return (unsigned short)((__float_as_uint(f) + 0x8000u) >> 16);
}

// ---------------- MFMA GEMM:  C[M,Nc] = A[M,K] @ B[Nc,K]^T + bias ----------------
// 128x128 block tile, 256 thr (2x2 waves of 64x64), BK=32.
// LDS fragment-slot layout: slot(row,kg) = (row>>4)*64 + kg*16 + (row&15); 8 bf16/slot.
// MFMA lane reads slot base + (lane>>4)*16 + (lane&15) -> lane-sequential b128 (conflict-free).
template <bool A_BF16, bool C_F32>
__global__ __launch_bounds__(256) void gemm_mfma(
    const void* __restrict__ Av, const float* __restrict__ B,
    const float* __restrict__ bias, void* __restrict__ Cv,
    int M, int Nc, int K)
{
    __shared__ __align__(16) unsigned short Al[512 * 8];  // 8KB
    __shared__ __align__(16) unsigned short Bl[512 * 8];  // 8KB

    const int t    = threadIdx.x;
    const int wave = t >> 6, lane = t & 63;
    const int wm   = wave >> 1, wn = wave & 1;
    const int m0   = blockIdx.y * 128, n0 = blockIdx.x * 128;

    const int srow  = t >> 1;                                   // staging row 0..127
    const int skh   = t & 1;                                    // k-half (16 elems)
    const int sslot = (srow >> 4) * 64 + (skh * 2) * 16 + (srow & 15);

    v4f acc[4][4];
#pragma unroll
    for (int i = 0; i < 4; ++i)
#pragma unroll
        for (int j = 0; j < 4; ++j) acc[i][j] = (v4f){0.f, 0.f, 0.f, 0.f};

    const unsigned short* pa_u = (const unsigned short*)Av + (size_t)(m0 + srow) * K + skh * 16;
    const float*          pa_f = (const float*)Av          + (size_t)(m0 + srow) * K + skh * 16;
    const float*          pb   = B                          + (size_t)(n0 + srow) * K + skh * 16;

    // lane's fragment byte offsets (4 m-subtiles / 4 n-subtiles)
    const int fbase = ((lane >> 4) * 16 + (lane & 15)) * 8;  // ushort index within rowgroup

    for (int k0 = 0; k0 < K; k0 += 32) {
        unsigned short a16[16], b16[16];
        if (A_BF16) {
            uint4 r0 = *(const uint4*)(pa_u + k0);
            uint4 r1 = *(const uint4*)(pa_u + k0 + 8);
            *(uint4*)&a16[0] = r0; *(uint4*)&a16[8] = r1;
        } else {
            float4 f0 = *(const float4*)(pa_f + k0);
            float4 f1 = *(const float4*)(pa_f + k0 + 4);
            float4 f2 = *(const float4*)(pa_f + k0 + 8);
            float4 f3 = *(const float4*)(pa_f + k0 + 12);
            a16[0] = f2bf_rh(f0.x); a16[1] = f2bf_rh(f0.y); a16[2] = f2bf_rh(f0.z); a16[3] = f2bf_rh(f0.w);
            a16[4] = f2bf_rh(f1.x); a16[5] = f2bf_rh(f1.y); a16[6] = f2bf_rh(f1.z); a16[7] = f2bf_rh(f1.w);
            a16[8] = f2bf_rh(f2.x); a16[9] = f2bf_rh(f2.y); a16[10] = f2bf_rh(f2.z); a16[11] = f2bf_rh(f2.w);
            a16[12] = f2bf_rh(f3.x); a16[13] = f2bf_rh(f3.y); a16[14] = f2bf_rh(f3.z); a16[15] = f2bf_rh(f3.w);
        }
        {
            float4 g0 = *(const float4*)(pb + k0);
            float4 g1 = *(const float4*)(pb + k0 + 4);
            float4 g2 = *(const float4*)(pb + k0 + 8);
            float4 g3 = *(const float4*)(pb + k0 + 12);
            b16[0] = f2bf_rh(g0.x); b16[1] = f2bf_rh(g0.y); b16[2] = f2bf_rh(g0.z); b16[3] = f2bf_rh(g0.w);
            b16[4] = f2bf_rh(g1.x); b16[5] = f2bf_rh(g1.y); b16[6] = f2bf_rh(g1.z); b16[7] = f2bf_rh(g1.w);
            b16[8] = f2bf_rh(g2.x); b16[9] = f2bf_rh(g2.y); b16[10] = f2bf_rh(g2.z); b16[11] = f2bf_rh(g2.w);
            b16[12] = f2bf_rh(g3.x); b16[13] = f2bf_rh(g3.y); b16[14] = f2bf_rh(g3.z); b16[15] = f2bf_rh(g3.w);
        }
        __syncthreads();
        *(uint4*)&Al[sslot * 8]        = *(uint4*)&a16[0];
        *(uint4*)&Al[(sslot + 16) * 8] = *(uint4*)&a16[8];
        *(uint4*)&Bl[sslot * 8]        = *(uint4*)&b16[0];
        *(uint4*)&Bl[(sslot + 16) * 8] = *(uint4*)&b16[8];
        __syncthreads();

        v8s af[4], bf[4];
#pragma unroll
        for (int ms = 0; ms < 4; ++ms)
            af[ms] = *(const v8s*)&Al[(wm * 4 + ms) * 64 * 8 + fbase];
#pragma unroll
        for (int ns = 0; ns < 4; ++ns)
            bf[ns] = *(const v8s*)&Bl[(wn * 4 + ns) * 64 * 8 + fbase];
#pragma unroll
        for (int ms = 0; ms < 4; ++ms)
#pragma unroll
            for (int ns = 0; ns < 4; ++ns)
                acc[ms][ns] = __builtin_amdgcn_mfma_f32_16x16x32_bf16(
                    af[ms], bf[ns], acc[ms][ns], 0, 0, 0);
    }

    // epilogue: C row = m0+wm*64+ms*16+(lane>>4)*4+reg, col = n0+wn*64+ns*16+(lane&15)
    float bn[4];
#pragma unroll
    for (int ns = 0; ns < 4; ++ns) bn[ns] = bias[n0 + wn * 64 + ns * 16 + (lane & 15)];

#pragma unroll
    for (int ms = 0; ms < 4; ++ms) {
#pragma unroll
        for (int reg = 0; reg < 4; ++reg) {
            const int row = m0 + wm * 64 + ms * 16 + (lane >> 4) * 4 + reg;
            const size_t base = (size_t)row * Nc + n0 + wn * 64 + (lane & 15);
#pragma unroll
            for (int ns = 0; ns < 4; ++ns) {
                float v = acc[ms][ns][reg] + bn[ns];
                if (C_F32) ((float*)Cv)[base + ns * 16] = v;
                else       ((unsigned short*)Cv)[base + ns * 16] = f2bf(v);
            }
        }
    }
}

// ---------------- Flash attention, key-split across 4 waves + merge ----------------
// grid (N/64=32, B*H=64), block 256 (4 waves). All waves share the q-tile
// (qi = blockIdx.x*64 + lane); wave w processes 32-key tiles kt32 = w, w+4, ...
// <= 2*qt+1. Per-wave online softmax; (m,l,o) merged through LDS at the end.
// kqv layout: [b*N+n][h*192 + e], e: k 0..63, q 64..127, v 128..191 (bf16).
__global__ __launch_bounds__(256) void attn(
    const unsigned short* __restrict__ kqv,
    unsigned short* __restrict__ sa)
{
    __shared__ union {
        float kv[2][4][32][64];   // [K/V][tile][key][dim]  64KB
        float osh[4][64][68];     // merge dump (68: 16B-aligned rows) 69.6KB
    } U;
    __shared__ float Msh[4][64], Lsh[4][64];

    const int t = threadIdx.x, w = t >> 6, lane = t & 63;
    const int bh = blockIdx.y, b = bh >> 4, h = bh & 15;
    const int qt = blockIdx.x;
    const int qi = qt * 64 + lane;

    const float MASKV = -1e30f;

    const size_t qrow = ((size_t)b * NSEQ + qi) * KQV_COLS + h * 192;
    float q[64];
#pragma unroll
    for (int u = 0; u < 16; ++u) {
        ushort4 v4 = *(const ushort4*)(kqv + qrow + 64 + u * 4);
        q[u * 4 + 0] = bf2f(v4.x); q[u * 4 + 1] = bf2f(v4.y);
        q[u * 4 + 2] = bf2f(v4.z); q[u * 4 + 3] = bf2f(v4.w);
    }
    float o[64];
#pragma unroll
    for (int d = 0; d < 64; ++d) o[d] = 0.f;
    float m = MASKV, l = 0.f;

    const int ktmax = 2 * qt + 1;            // last 32-key tile
    const int iters = (ktmax + 4) >> 2;      // ceil((ktmax+1)/4), block-uniform
    for (int it = 0; it < iters; ++it) {
        __syncthreads();
        // stage 128 keys (K and V) -> fp32 LDS; 16 quads/thread, coalesced b64 reads
#pragma unroll 4
        for (int i = 0; i < 16; ++i) {
            int p   = t + i * 256;           // 0..4095
            int isv = p >> 11;               // 0 = K, 1 = V
            int rem = p & 2047;
            int key = rem >> 4;              // 0..127
            int dq  = (rem & 15) << 2;
            const size_t grow = ((size_t)b * NSEQ + it * 128 + key) * KQV_COLS
                              + h * 192 + (isv ? 128 : 0) + dq;
            ushort4 u4 = *(const ushort4*)(kqv + grow);
            float4 fv;
            fv.x = bf2f(u4.x); fv.y = bf2f(u4.y); fv.z = bf2f(u4.z); fv.w = bf2f(u4.w);
            *(float4*)&U.kv[isv][key >> 5][key & 31][dq] = fv;
        }
        __syncthreads();

        const int kt32 = it * 4 + w;
        if (kt32 > ktmax) continue;          // no barriers below in this loop
        const int kbase = kt32 * 32;
#pragma unroll
        for (int c0 = 0; c0 < 32; c0 += 16) {
            float s[16];
#pragma unroll
            for (int j = 0; j < 16; ++j) {
                const int kj = c0 + j;
                float a2 = 0.f;
#pragma unroll
                for (int d4 = 0; d4 < 64; d4 += 4) {
                    float4 kv4 = *(const float4*)&U.kv[0][w][kj][d4];
                    a2 = fmaf(q[d4 + 0], kv4.x, a2);
                    a2 = fmaf(q[d4 + 1], kv4.y, a2);
                    a2 = fmaf(q[d4 + 2], kv4.z, a2);
                    a2 = fmaf(q[d4 + 3], kv4.w, a2);
                }
                s[j] = (kbase + kj <= qi) ? a2 * 0.125f : MASKV;
            }
            float mx = s[0];
#pragma unroll
            for (int j = 1; j < 16; ++j) mx = fmaxf(mx, s[j]);
            const float m_new = fmaxf(m, mx);
            if (m_new == MASKV) continue;
            const float alpha = __expf(m - m_new);
            float sum = 0.f;
#pragma unroll
            for (int j = 0; j < 16; ++j) { s[j] = __expf(s[j] - m_new); sum += s[j]; }
            l = l * alpha + sum;
            m = m_new;
#pragma unroll
            for (int d = 0; d < 64; ++d) o[d] *= alpha;
#pragma unroll
            for (int j = 0; j < 16; ++j) {
                const float pj = s[j];
#pragma unroll
                for (int d4 = 0; d4 < 64; d4 += 4) {
                    float4 vv = *(const float4*)&U.kv[1][w][c0 + j][d4];
                    o[d4 + 0] = fmaf(pj, vv.x, o[d4 + 0]);
                    o[d4 + 1] = fmaf(pj, vv.y, o[d4 + 1]);
                    o[d4 + 2] = fmaf(pj, vv.z, o[d4 + 2]);
                    o[d4 + 3] = fmaf(pj, vv.w, o[d4 + 3]);
                }
            }
        }
    }

    // ---- merge the 4 per-wave partial (m,l,o) states ----
    __syncthreads();   // K/V reads done; reuse union as osh
    Msh[w][lane] = m; Lsh[w][lane] = l;
#pragma unroll
    for (int d4 = 0; d4 < 64; d4 += 4)
        *(float4*)&U.osh[w][lane][d4] = *(const float4*)&o[d4];
    __syncthreads();

    float mw[4], aw[4];
#pragma unroll
    for (int ww = 0; ww < 4; ++ww) mw[ww] = Msh[ww][lane];
    float mstar = fmaxf(fmaxf(mw[0], mw[1]), fmaxf(mw[2], mw[3]));
    float lstar = 0.f;
#pragma unroll
    for (int ww = 0; ww < 4; ++ww) {
        aw[ww] = __expf(mw[ww] - mstar);     // MASKV wave -> 0
        lstar += aw[ww] * Lsh[ww][lane];
    }
    const float inv = 1.f / lstar;           // >= 1 (diagonal always present)

    // wave w reduces dims [w*16, w*16+16) for its lane's query
    float4 r[4];
#pragma unroll
    for (int j = 0; j < 4; ++j) r[j] = (float4){0.f, 0.f, 0.f, 0.f};
#pragma unroll
    for (int ww = 0; ww < 4; ++ww) {
        const float a = aw[ww];
#pragma unroll
        for (int j = 0; j < 4; ++j) {
            float4 v = *(const float4*)&U.osh[ww][lane][w * 16 + j * 4];
            r[j].x = fmaf(a, v.x, r[j].x); r[j].y = fmaf(a, v.y, r[j].y);
            r[j].z = fmaf(a, v.z, r[j].z); r[j].w = fmaf(a, v.w, r[j].w);
        }
    }
    const size_t orow = ((size_t)b * NSEQ + qi) * DMODEL + h * 64 + w * 16;
#pragma unroll
    for (int j = 0; j < 4; ++j) {
        ushort4 w4;
        w4.x = f2bf(r[j].x * inv); w4.y = f2bf(r[j].y * inv);
        w4.z = f2bf(r[j].z * inv); w4.w = f2bf(r[j].w * inv);
        *(ushort4*)(sa + orow + j * 4) = w4;
    }
}

extern "C" void kernel_launch(void* const* d_in, const int* in_sizes, int n_in,
                              void* d_out, int out_size, void* d_ws, size_t ws_size,
                              hipStream_t stream) {
    const float* x     = (const float*)d_in[0];  // [4,2048,1024]
    const float* Wkqv  = (const float*)d_in[1];  // [16,192,1024]
    const float* bkqv  = (const float*)d_in[2];  // [16,192]
    const float* Wproj = (const float*)d_in[3];  // [1024,1024]
    const float* bproj = (const float*)d_in[4];  // [1024]
    float* out = (float*)d_out;                  // [4,2048,1024] fp32

    unsigned short* kqv = (unsigned short*)d_ws;          // [8192,3072] bf16
    unsigned short* sa  = kqv + (size_t)8192 * KQV_COLS;  // [8192,1024] bf16

    // 1) kqv = x @ Wkqv^T + bkqv   (A fp32 -> cvt staging, C bf16)
    gemm_mfma<false, false><<<dim3(KQV_COLS / 128, 8192 / 128), 256, 0, stream>>>(
        x, Wkqv, bkqv, kqv, 8192, KQV_COLS, 1024);
    // 2) attention -> sa
    attn<<<dim3(NSEQ / 64, 4 * NHEAD), 256, 0, stream>>>(kqv, sa);
    // 3) out = sa @ Wproj^T + bproj (A bf16 raw staging, C fp32)
    gemm_mfma<true, true><<<dim3(DMODEL / 128, 8192 / 128), 256, 0, stream>>>(
        sa, Wproj, bproj, out, 8192, DMODEL, 1024);
}

// Round 5
// 358.365 us; speedup vs baseline: 18.2009x; 18.2009x over previous
//
#include <hip/hip_runtime.h>
#include <hip/hip_bf16.h>

// CausalSelfAttention: B=4, N=2048, D=1024, H=16, HD=64. fp32 in / fp32 out.
// R5: MFMA everywhere.
//   gemm1 (EPI=1): kqv GEMM, epilogue splits into Kbuf[bh][n][64], Qbuf[bh][n][64],
//                  VT[bh][d][2048] (V transposed at write time -> attn staging is
//                  pure b128 copies, no transpose).
//   attn_mfma:     flash attention on mfma_f32_16x16x32_bf16. Block = 4 waves =
//                  one 64-query tile; wave = 16 queries (A-frag). Blocks process
//                  paired q-tiles (qt, 31-qt) -> uniform 33 key-tiles/block,
//                  1024 blocks = exactly 4/CU. P routed C-layout->LDS->A-layout.
//   gemm3 (EPI=2): out = sa @ Wproj^T + bproj (fp32 C).
// ws: Kbuf 16.78 + Qbuf 16.78 + VT 16.78 + sa 16.78 MB = exactly 64 MiB.
// Fragment layouts HW-verified by R4's passing GEMM:
//   A[m=lane&15][k=quad*8+j], B[n=lane&15][k=quad*8+j], C col=lane&15 row=quad*4+reg.

#define NSEQ 2048
#define NHEAD 16
#define DMODEL 1024

typedef __attribute__((ext_vector_type(8))) short v8s;  // 8 bf16 = 4 VGPRs
typedef __attribute__((ext_vector_type(4))) float v4f;  // MFMA acc

__device__ __forceinline__ float bf2f(unsigned short u) {
    union { unsigned int i; float f; } v;
    v.i = ((unsigned int)u) << 16;
    return v.f;
}
__device__ __forceinline__ unsigned short f2bf(float f) {  // RNE
    unsigned int x = __float_as_uint(f);
    return (unsigned short)((x + 0x7fffu + ((x >> 16) & 1u)) >> 16);
}
__device__ __forceinline__ unsigned short f2bf_rh(float f) {  // round-half-up (staging)
    return (unsigned short)((__float_as_uint(f) + 0x8000u) >> 16);
}

// ---------------- MFMA GEMM core (R4-validated), 2 epilogues ----------------
// C[M,Nc] = A[M,K] @ B[Nc,K]^T + bias. 128x128 tile, 256 thr, BK=32.
// EPI=1: split-write Kbuf/Qbuf/VT (kqv gemm, Nc=3072, cols = h*192+e).
// EPI=2: plain fp32 C (proj gemm).
template <bool A_BF16, int EPI>
__global__ __launch_bounds__(256) void gemm_mfma(
    const void* __restrict__ Av, const float* __restrict__ B,
    const float* __restrict__ bias,
    float* __restrict__ Cf,                 // EPI=2
    unsigned short* __restrict__ Kb,        // EPI=1
    unsigned short* __restrict__ Qb,        // EPI=1
    unsigned short* __restrict__ VTb,       // EPI=1
    int M, int Nc, int K)
{
    __shared__ __align__(16) unsigned short Al[512 * 8];
    __shared__ __align__(16) unsigned short Bl[512 * 8];

    const int t    = threadIdx.x;
    const int wave = t >> 6, lane = t & 63;
    const int wm   = wave >> 1, wn = wave & 1;
    const int m0   = blockIdx.y * 128, n0 = blockIdx.x * 128;
    const int quad = lane >> 4, c = lane & 15;

    const int srow  = t >> 1;
    const int skh   = t & 1;
    const int sslot = (srow >> 4) * 64 + (skh * 2) * 16 + (srow & 15);

    v4f acc[4][4];
#pragma unroll
    for (int i = 0; i < 4; ++i)
#pragma unroll
        for (int j = 0; j < 4; ++j) acc[i][j] = (v4f){0.f, 0.f, 0.f, 0.f};

    const unsigned short* pa_u = (const unsigned short*)Av + (size_t)(m0 + srow) * K + skh * 16;
    const float*          pa_f = (const float*)Av          + (size_t)(m0 + srow) * K + skh * 16;
    const float*          pb   = B                          + (size_t)(n0 + srow) * K + skh * 16;

    const int fbase = (quad * 16 + c) * 8;

    for (int k0 = 0; k0 < K; k0 += 32) {
        unsigned short a16[16], b16[16];
        if (A_BF16) {
            uint4 r0 = *(const uint4*)(pa_u + k0);
            uint4 r1 = *(const uint4*)(pa_u + k0 + 8);
            *(uint4*)&a16[0] = r0; *(uint4*)&a16[8] = r1;
        } else {
            float4 f0 = *(const float4*)(pa_f + k0);
            float4 f1 = *(const float4*)(pa_f + k0 + 4);
            float4 f2 = *(const float4*)(pa_f + k0 + 8);
            float4 f3 = *(const float4*)(pa_f + k0 + 12);
            a16[0] = f2bf_rh(f0.x); a16[1] = f2bf_rh(f0.y); a16[2] = f2bf_rh(f0.z); a16[3] = f2bf_rh(f0.w);
            a16[4] = f2bf_rh(f1.x); a16[5] = f2bf_rh(f1.y); a16[6] = f2bf_rh(f1.z); a16[7] = f2bf_rh(f1.w);
            a16[8] = f2bf_rh(f2.x); a16[9] = f2bf_rh(f2.y); a16[10] = f2bf_rh(f2.z); a16[11] = f2bf_rh(f2.w);
            a16[12] = f2bf_rh(f3.x); a16[13] = f2bf_rh(f3.y); a16[14] = f2bf_rh(f3.z); a16[15] = f2bf_rh(f3.w);
        }
        {
            float4 g0 = *(const float4*)(pb + k0);
            float4 g1 = *(const float4*)(pb + k0 + 4);
            float4 g2 = *(const float4*)(pb + k0 + 8);
            float4 g3 = *(const float4*)(pb + k0 + 12);
            b16[0] = f2bf_rh(g0.x); b16[1] = f2bf_rh(g0.y); b16[2] = f2bf_rh(g0.z); b16[3] = f2bf_rh(g0.w);
            b16[4] = f2bf_rh(g1.x); b16[5] = f2bf_rh(g1.y); b16[6] = f2bf_rh(g1.z); b16[7] = f2bf_rh(g1.w);
            b16[8] = f2bf_rh(g2.x); b16[9] = f2bf_rh(g2.y); b16[10] = f2bf_rh(g2.z); b16[11] = f2bf_rh(g2.w);
            b16[12] = f2bf_rh(g3.x); b16[13] = f2bf_rh(g3.y); b16[14] = f2bf_rh(g3.z); b16[15] = f2bf_rh(g3.w);
        }
        __syncthreads();
        *(uint4*)&Al[sslot * 8]        = *(uint4*)&a16[0];
        *(uint4*)&Al[(sslot + 16) * 8] = *(uint4*)&a16[8];
        *(uint4*)&Bl[sslot * 8]        = *(uint4*)&b16[0];
        *(uint4*)&Bl[(sslot + 16) * 8] = *(uint4*)&b16[8];
        __syncthreads();

        v8s af[4], bf[4];
#pragma unroll
        for (int ms = 0; ms < 4; ++ms)
            af[ms] = *(const v8s*)&Al[(wm * 4 + ms) * 64 * 8 + fbase];
#pragma unroll
        for (int ns = 0; ns < 4; ++ns)
            bf[ns] = *(const v8s*)&Bl[(wn * 4 + ns) * 64 * 8 + fbase];
#pragma unroll
        for (int ms = 0; ms < 4; ++ms)
#pragma unroll
            for (int ns = 0; ns < 4; ++ns)
                acc[ms][ns] = __builtin_amdgcn_mfma_f32_16x16x32_bf16(
                    af[ms], bf[ns], acc[ms][ns], 0, 0, 0);
    }

    float bn[4];
#pragma unroll
    for (int ns = 0; ns < 4; ++ns) bn[ns] = bias[n0 + wn * 64 + ns * 16 + c];

#pragma unroll
    for (int ms = 0; ms < 4; ++ms) {
        const int row0 = m0 + wm * 64 + ms * 16 + quad * 4;  // 4 consecutive tokens
#pragma unroll
        for (int ns = 0; ns < 4; ++ns) {
            float v0 = acc[ms][ns][0] + bn[ns];
            float v1 = acc[ms][ns][1] + bn[ns];
            float v2 = acc[ms][ns][2] + bn[ns];
            float v3 = acc[ms][ns][3] + bn[ns];
            if (EPI == 2) {
                float* pc = Cf + (size_t)row0 * Nc + n0 + wn * 64 + ns * 16 + c;
                pc[0] = v0; pc[(size_t)Nc] = v1;
                pc[(size_t)2 * Nc] = v2; pc[(size_t)3 * Nc] = v3;
            } else {
                const int colbase = n0 + wn * 64 + ns * 16;   // block-uniform
                const int hh = colbase / 192;
                const int eb = colbase - hh * 192;            // 16-aligned, class-uniform
                const int bb = row0 >> 11, tok0 = row0 & 2047;
                const int bhh = bb * 16 + hh;
                if (eb >= 128) {                              // V -> transposed
                    ushort4 pk;
                    pk.x = f2bf(v0); pk.y = f2bf(v1); pk.z = f2bf(v2); pk.w = f2bf(v3);
                    *(ushort4*)(VTb + ((size_t)bhh * 64 + (eb - 128) + c) * 2048 + tok0) = pk;
                } else {
                    unsigned short* dst = (eb < 64) ? Kb : Qb;
                    const int e = (eb < 64 ? eb : eb - 64) + c;
                    const size_t base = ((size_t)bhh * 2048 + tok0) * 64 + e;
                    dst[base]       = f2bf(v0);
                    dst[base + 64]  = f2bf(v1);
                    dst[base + 128] = f2bf(v2);
                    dst[base + 192] = f2bf(v3);
                }
            }
        }
    }
}

// ---------------- MFMA flash attention ----------------
// grid (16, 64), block 256. Phases: qt = bx, then 31-bx (uniform 33 tiles/block).
// Wave w: queries qt*64 + w*16 + (0..15). K-tiles of 64 keys staged in LDS.
// kqv scale 1/sqrt(64) = 0.125 applied to scores.
#define ATTS 72  // LDS row stride in shorts (144B: 16B-aligned, conflict-free)

__global__ __launch_bounds__(256, 4) void attn_mfma(
    const unsigned short* __restrict__ Kbuf,  // [64][2048][64]
    const unsigned short* __restrict__ Qbuf,  // [64][2048][64]
    const unsigned short* __restrict__ VT,    // [64][64][2048]
    unsigned short* __restrict__ sa)          // [8192][1024]
{
    __shared__ __align__(16) unsigned short Ks[64 * ATTS];
    __shared__ __align__(16) unsigned short Vt[64 * ATTS];
    __shared__ __align__(16) unsigned short Ps[4][16 * ATTS];

    const int t = threadIdx.x, w = t >> 6, lane = t & 63;
    const int quad = lane >> 4, c = lane & 15;
    const int bh = blockIdx.y;
    const int b = bh >> 4, hh = bh & 15;
    const size_t gbase = (size_t)bh * 2048 * 64;   // Kbuf/Qbuf/VT per-bh base

    const int skey = t >> 2, sdg = t & 3;          // staging row / 16-col group

#pragma unroll 1
    for (int phase = 0; phase < 2; ++phase) {
        const int qt = (phase == 0) ? blockIdx.x : 31 - blockIdx.x;

        // Q fragments (A-operand) straight from global
        const size_t qr = gbase + (size_t)(qt * 64 + w * 16 + c) * 64 + quad * 8;
        v8s qf0 = *(const v8s*)(Qbuf + qr);
        v8s qf1 = *(const v8s*)(Qbuf + qr + 32);

        v4f oacc[4];
#pragma unroll
        for (int dn = 0; dn < 4; ++dn) oacc[dn] = (v4f){0.f, 0.f, 0.f, 0.f};
        float mrow[4] = {-1e30f, -1e30f, -1e30f, -1e30f};
        float lrow[4] = {0.f, 0.f, 0.f, 0.f};

        for (int kt = 0; kt <= qt; ++kt) {
            __syncthreads();
            {   // stage K tile (row-major) and V^T tile (already transposed in ws)
                const unsigned short* sk = Kbuf + gbase + (size_t)(kt * 64 + skey) * 64 + sdg * 16;
                uint4 k0 = *(const uint4*)sk;
                uint4 k1 = *(const uint4*)(sk + 8);
                *(uint4*)&Ks[skey * ATTS + sdg * 16]     = k0;
                *(uint4*)&Ks[skey * ATTS + sdg * 16 + 8] = k1;
                const unsigned short* sv = VT + gbase + (size_t)skey * 2048 + kt * 64 + sdg * 16;
                uint4 u0 = *(const uint4*)sv;
                uint4 u1 = *(const uint4*)(sv + 8);
                *(uint4*)&Vt[skey * ATTS + sdg * 16]     = u0;
                *(uint4*)&Vt[skey * ATTS + sdg * 16 + 8] = u1;
            }
            __syncthreads();

            // S = Q K^T  (4 key-subtiles)
            v4f s[4];
#pragma unroll
            for (int kn = 0; kn < 4; ++kn) {
                s[kn] = (v4f){0.f, 0.f, 0.f, 0.f};
                v8s kf0 = *(const v8s*)&Ks[(kn * 16 + c) * ATTS + quad * 8];
                v8s kf1 = *(const v8s*)&Ks[(kn * 16 + c) * ATTS + 32 + quad * 8];
                s[kn] = __builtin_amdgcn_mfma_f32_16x16x32_bf16(qf0, kf0, s[kn], 0, 0, 0);
                s[kn] = __builtin_amdgcn_mfma_f32_16x16x32_bf16(qf1, kf1, s[kn], 0, 0, 0);
            }
            // scale + causal mask (only diagonal tile needs it)
            float sc[4][4];
#pragma unroll
            for (int kn = 0; kn < 4; ++kn)
#pragma unroll
                for (int r = 0; r < 4; ++r) sc[kn][r] = s[kn][r] * 0.125f;
            if (kt == qt) {
#pragma unroll
                for (int kn = 0; kn < 4; ++kn)
#pragma unroll
                    for (int r = 0; r < 4; ++r)
                        if (kn * 16 + c > w * 16 + quad * 4 + r) sc[kn][r] = -1e30f;
            }
            // row max over 64 keys (local over kn, then 16-lane row-group)
            float tm[4];
#pragma unroll
            for (int r = 0; r < 4; ++r)
                tm[r] = fmaxf(fmaxf(sc[0][r], sc[1][r]), fmaxf(sc[2][r], sc[3][r]));
#pragma unroll
            for (int d = 1; d < 16; d <<= 1)
#pragma unroll
                for (int r = 0; r < 4; ++r) tm[r] = fmaxf(tm[r], __shfl_xor(tm[r], d, 16));

            float alpha[4];
#pragma unroll
            for (int r = 0; r < 4; ++r) {
                float mn = fmaxf(mrow[r], tm[r]);
                alpha[r] = __expf(mrow[r] - mn);   // first tile: exp(-inf-ish)=0
                mrow[r] = mn;
            }
            float psum[4] = {0.f, 0.f, 0.f, 0.f};
#pragma unroll
            for (int kn = 0; kn < 4; ++kn)
#pragma unroll
                for (int r = 0; r < 4; ++r) {
                    float p = __expf(sc[kn][r] - mrow[r]);
                    psum[r] += p;
                    Ps[w][(quad * 4 + r) * ATTS + kn * 16 + c] = f2bf_rh(p);
                }
#pragma unroll
            for (int d = 1; d < 16; d <<= 1)
#pragma unroll
                for (int r = 0; r < 4; ++r) psum[r] += __shfl_xor(psum[r], d, 16);
#pragma unroll
            for (int r = 0; r < 4; ++r) lrow[r] = lrow[r] * alpha[r] + psum[r];
#pragma unroll
            for (int dn = 0; dn < 4; ++dn)
#pragma unroll
                for (int r = 0; r < 4; ++r) oacc[dn][r] *= alpha[r];

            // P: C-layout -> (LDS, per-wave) -> A-layout; then O += P V
            v8s pa0 = *(const v8s*)&Ps[w][c * ATTS + quad * 8];
            v8s pa1 = *(const v8s*)&Ps[w][c * ATTS + 32 + quad * 8];
#pragma unroll
            for (int dn = 0; dn < 4; ++dn) {
                v8s vf0 = *(const v8s*)&Vt[(dn * 16 + c) * ATTS + quad * 8];
                v8s vf1 = *(const v8s*)&Vt[(dn * 16 + c) * ATTS + 32 + quad * 8];
                oacc[dn] = __builtin_amdgcn_mfma_f32_16x16x32_bf16(pa0, vf0, oacc[dn], 0, 0, 0);
                oacc[dn] = __builtin_amdgcn_mfma_f32_16x16x32_bf16(pa1, vf1, oacc[dn], 0, 0, 0);
            }
        }

        // epilogue: sa[b, qt*64 + w*16 + quad*4 + r, hh*64 + dn*16 + c]
        float inv[4];
#pragma unroll
        for (int r = 0; r < 4; ++r) inv[r] = 1.f / lrow[r];
        const size_t obase = ((size_t)(b * 2048 + qt * 64 + w * 16 + quad * 4)) * DMODEL + hh * 64;
#pragma unroll
        for (int dn = 0; dn < 4; ++dn)
#pragma unroll
            for (int r = 0; r < 4; ++r)
                sa[obase + (size_t)r * DMODEL + dn * 16 + c] = f2bf(oacc[dn][r] * inv[r]);
    }
}

extern "C" void kernel_launch(void* const* d_in, const int* in_sizes, int n_in,
                              void* d_out, int out_size, void* d_ws, size_t ws_size,
                              hipStream_t stream) {
    const float* x     = (const float*)d_in[0];  // [4,2048,1024]
    const float* Wkqv  = (const float*)d_in[1];  // [16,192,1024] -> flat [3072,1024]
    const float* bkqv  = (const float*)d_in[2];  // [16,192] -> flat [3072]
    const float* Wproj = (const float*)d_in[3];  // [1024,1024]
    const float* bproj = (const float*)d_in[4];  // [1024]
    float* out = (float*)d_out;                  // [4,2048,1024] fp32

    unsigned short* Kb = (unsigned short*)d_ws;            // [64][2048][64] 16.78MB
    unsigned short* Qb = Kb + (size_t)64 * 2048 * 64;      // [64][2048][64]
    unsigned short* VT = Qb + (size_t)64 * 2048 * 64;      // [64][64][2048]
    unsigned short* sa = VT + (size_t)64 * 2048 * 64;      // [8192][1024]

    // 1) kqv GEMM, split epilogue -> Kb/Qb/VT
    gemm_mfma<false, 1><<<dim3(3072 / 128, 8192 / 128), 256, 0, stream>>>(
        x, Wkqv, bkqv, nullptr, Kb, Qb, VT, 8192, 3072, 1024);
    // 2) MFMA flash attention -> sa
    attn_mfma<<<dim3(16, 64), 256, 0, stream>>>(Kb, Qb, VT, sa);
    // 3) out = sa @ Wproj^T + bproj
    gemm_mfma<true, 2><<<dim3(DMODEL / 128, 8192 / 128), 256, 0, stream>>>(
        sa, Wproj, bproj, out, nullptr, nullptr, nullptr, 8192, DMODEL, 1024);
}

// Round 6
// 349.083 us; speedup vs baseline: 18.6848x; 1.0266x over previous
//
#include <hip/hip_runtime.h>
#include <hip/hip_bf16.h>

// CausalSelfAttention: B=4, N=2048, D=1024, H=16, HD=64. fp32 in / fp32 out.
// R6: (1) pre-convert x/W to bf16 (host-gated on ws_size >= 72MiB; fallback = R5 gemms);
//     (2) GEMMs use global_load_lds width-16 DMA straight into the verified
//         fragment-slot LDS layout (zero staging VALU / ds_writes);
//     (3) attn: 128-query blocks (4 waves x 32q, kf/vf reads + staging amortized 2x),
//         XOR chunk-swizzle on Ks/Vt/Ps staging (kills the 4-way write conflicts).
// ws: Kb/Qb/VT/sa 4x16.777MB = 64MiB; fast path adds wkb 6.29MB + wpb 2.10MB = 72MiB.
// xb (bf16 x) overlaps sa (dead until attn).

#define NSEQ 2048
#define NHEAD 16
#define DMODEL 1024

typedef __attribute__((ext_vector_type(8))) short v8s;  // 8 bf16 = 4 VGPRs
typedef __attribute__((ext_vector_type(4))) float v4f;  // MFMA acc

__device__ __forceinline__ float bf2f(unsigned short u) {
    union { unsigned int i; float f; } v;
    v.i = ((unsigned int)u) << 16;
    return v.f;
}
__device__ __forceinline__ unsigned short f2bf(float f) {  // RNE
    unsigned int x = __float_as_uint(f);
    return (unsigned short)((x + 0x7fffu + ((x >> 16) & 1u)) >> 16);
}
__device__ __forceinline__ unsigned short f2bf_rh(float f) {  // round-half-up (staging)
    return (unsigned short)((__float_as_uint(f) + 0x8000u) >> 16);
}
__device__ __forceinline__ void gld_lds16(const unsigned short* g, unsigned short* l) {
    __builtin_amdgcn_global_load_lds(
        (const __attribute__((address_space(1))) void*)g,
        (__attribute__((address_space(3))) void*)l, 16, 0, 0);
}

// ---------------- cvt: fp32 -> bf16 for x, Wkqv, Wproj (one pass) ----------------
__global__ __launch_bounds__(256) void cvt_bf16(
    const float* __restrict__ x, const float* __restrict__ wk, const float* __restrict__ wp,
    unsigned short* __restrict__ xb, unsigned short* __restrict__ wkb,
    unsigned short* __restrict__ wpb)
{
    const int i = blockIdx.x * 256 + threadIdx.x;   // quad index, total 3145728 exact
    const float* s; unsigned short* d; int o;
    if (i < 2097152)      { s = x;  d = xb;  o = i; }
    else if (i < 2883584) { s = wk; d = wkb; o = i - 2097152; }
    else                  { s = wp; d = wpb; o = i - 2883584; }
    float4 f = ((const float4*)s)[o];
    ushort4 u;
    u.x = f2bf(f.x); u.y = f2bf(f.y); u.z = f2bf(f.z); u.w = f2bf(f.w);
    ((ushort4*)d)[o] = u;
}

// ---------------- fast MFMA GEMM: bf16 A/B, global_load_lds staging ----------------
// C[M,Nc] = A[M,K] @ B[Nc,K]^T + bias. 128x128 tile, 256 thr, BK=32.
// LDS fragment-slot layout (R4/5-verified): slot(row,kg) = (row>>4)*64 + kg*16 + (row&15).
// DMA: instr for rowgroup g covers slots g*64+lane -> lane (kg=(lane>>4)&3, r15=lane&15)
// fetches A[(m0+g*16+r15)*K + kg*8 + k0] (16B) -> LDS base+lane*16 = slot order. 
// EPI=1: split-write Kb/Qb/VT (kqv gemm). EPI=2: plain fp32 C (proj gemm).
template <int EPI>
__global__ __launch_bounds__(256) void gemm_lds(
    const unsigned short* __restrict__ A, const unsigned short* __restrict__ B,
    const float* __restrict__ bias,
    float* __restrict__ Cf,
    unsigned short* __restrict__ Kb, unsigned short* __restrict__ Qb,
    unsigned short* __restrict__ VTb,
    int M, int Nc, int K)
{
    __shared__ __align__(16) unsigned short Al[512 * 8];  // 8KB
    __shared__ __align__(16) unsigned short Bl[512 * 8];  // 8KB

    const int t = threadIdx.x, wave = t >> 6, lane = t & 63;
    const int wm = wave >> 1, wn = wave & 1;
    const int m0 = blockIdx.y * 128, n0 = blockIdx.x * 128;
    const int quad = lane >> 4, c = lane & 15;

    // DMA source/dest (wave handles rowgroups wave*2, wave*2+1 of A and B)
    const int g0 = wave * 2, g1 = wave * 2 + 1;
    const int r15 = lane & 15, kg = (lane >> 4) & 3;
    const unsigned short* sA0 = A + (size_t)(m0 + g0 * 16 + r15) * K + kg * 8;
    const unsigned short* sA1 = A + (size_t)(m0 + g1 * 16 + r15) * K + kg * 8;
    const unsigned short* sB0 = B + (size_t)(n0 + g0 * 16 + r15) * K + kg * 8;
    const unsigned short* sB1 = B + (size_t)(n0 + g1 * 16 + r15) * K + kg * 8;
    unsigned short* dA0 = &Al[g0 * 512];
    unsigned short* dA1 = &Al[g1 * 512];
    unsigned short* dB0 = &Bl[g0 * 512];
    unsigned short* dB1 = &Bl[g1 * 512];

    v4f acc[4][4];
#pragma unroll
    for (int i = 0; i < 4; ++i)
#pragma unroll
        for (int j = 0; j < 4; ++j) acc[i][j] = (v4f){0.f, 0.f, 0.f, 0.f};

    const int fbase = (quad * 16 + c) * 8;

    for (int k0 = 0; k0 < K; k0 += 32) {
        __syncthreads();                   // prior frag reads done before DMA overwrite
        gld_lds16(sA0 + k0, dA0);
        gld_lds16(sA1 + k0, dA1);
        gld_lds16(sB0 + k0, dB0);
        gld_lds16(sB1 + k0, dB1);
        __syncthreads();                   // vmcnt(0) drain: DMA visible

        v8s af[4], bf[4];
#pragma unroll
        for (int ms = 0; ms < 4; ++ms)
            af[ms] = *(const v8s*)&Al[(wm * 4 + ms) * 512 + fbase];
#pragma unroll
        for (int ns = 0; ns < 4; ++ns)
            bf[ns] = *(const v8s*)&Bl[(wn * 4 + ns) * 512 + fbase];
#pragma unroll
        for (int ms = 0; ms < 4; ++ms)
#pragma unroll
            for (int ns = 0; ns < 4; ++ns)
                acc[ms][ns] = __builtin_amdgcn_mfma_f32_16x16x32_bf16(
                    af[ms], bf[ns], acc[ms][ns], 0, 0, 0);
    }

    float bn[4];
#pragma unroll
    for (int ns = 0; ns < 4; ++ns) bn[ns] = bias[n0 + wn * 64 + ns * 16 + c];

#pragma unroll
    for (int ms = 0; ms < 4; ++ms) {
        const int row0 = m0 + wm * 64 + ms * 16 + quad * 4;
#pragma unroll
        for (int ns = 0; ns < 4; ++ns) {
            float v0 = acc[ms][ns][0] + bn[ns];
            float v1 = acc[ms][ns][1] + bn[ns];
            float v2 = acc[ms][ns][2] + bn[ns];
            float v3 = acc[ms][ns][3] + bn[ns];
            if (EPI == 2) {
                float* pc = Cf + (size_t)row0 * Nc + n0 + wn * 64 + ns * 16 + c;
                pc[0] = v0; pc[(size_t)Nc] = v1;
                pc[(size_t)2 * Nc] = v2; pc[(size_t)3 * Nc] = v3;
            } else {
                const int colbase = n0 + wn * 64 + ns * 16;
                const int hh = colbase / 192;
                const int eb = colbase - hh * 192;
                const int bb = row0 >> 11, tok0 = row0 & 2047;
                const int bhh = bb * 16 + hh;
                if (eb >= 128) {
                    ushort4 pk;
                    pk.x = f2bf(v0); pk.y = f2bf(v1); pk.z = f2bf(v2); pk.w = f2bf(v3);
                    *(ushort4*)(VTb + ((size_t)bhh * 64 + (eb - 128) + c) * 2048 + tok0) = pk;
                } else {
                    unsigned short* dst = (eb < 64) ? Kb : Qb;
                    const int e = (eb < 64 ? eb : eb - 64) + c;
                    const size_t base = ((size_t)bhh * 2048 + tok0) * 64 + e;
                    dst[base]       = f2bf(v0);
                    dst[base + 64]  = f2bf(v1);
                    dst[base + 128] = f2bf(v2);
                    dst[base + 192] = f2bf(v3);
                }
            }
        }
    }
}

// ---------------- fallback GEMM (R5, fp32 sources, VGPR-roundtrip staging) ----------
template <bool A_BF16, int EPI>
__global__ __launch_bounds__(256) void gemm_mfma(
    const void* __restrict__ Av, const float* __restrict__ B,
    const float* __restrict__ bias,
    float* __restrict__ Cf,
    unsigned short* __restrict__ Kb, unsigned short* __restrict__ Qb,
    unsigned short* __restrict__ VTb,
    int M, int Nc, int K)
{
    __shared__ __align__(16) unsigned short Al[512 * 8];
    __shared__ __align__(16) unsigned short Bl[512 * 8];

    const int t = threadIdx.x;
    const int wave = t >> 6, lane = t & 63;
    const int wm = wave >> 1, wn = wave & 1;
    const int m0 = blockIdx.y * 128, n0 = blockIdx.x * 128;
    const int quad = lane >> 4, c = lane & 15;

    const int srow = t >> 1, skh = t & 1;
    const int sslot = (srow >> 4) * 64 + (skh * 2) * 16 + (srow & 15);

    v4f acc[4][4];
#pragma unroll
    for (int i = 0; i < 4; ++i)
#pragma unroll
        for (int j = 0; j < 4; ++j) acc[i][j] = (v4f){0.f, 0.f, 0.f, 0.f};

    const unsigned short* pa_u = (const unsigned short*)Av + (size_t)(m0 + srow) * K + skh * 16;
    const float*          pa_f = (const float*)Av          + (size_t)(m0 + srow) * K + skh * 16;
    const float*          pb   = B                          + (size_t)(n0 + srow) * K + skh * 16;

    const int fbase = (quad * 16 + c) * 8;

    for (int k0 = 0; k0 < K; k0 += 32) {
        unsigned short a16[16], b16[16];
        if (A_BF16) {
            uint4 r0 = *(const uint4*)(pa_u + k0);
            uint4 r1 = *(const uint4*)(pa_u + k0 + 8);
            *(uint4*)&a16[0] = r0; *(uint4*)&a16[8] = r1;
        } else {
            float4 f0 = *(const float4*)(pa_f + k0);
            float4 f1 = *(const float4*)(pa_f + k0 + 4);
            float4 f2 = *(const float4*)(pa_f + k0 + 8);
            float4 f3 = *(const float4*)(pa_f + k0 + 12);
            a16[0] = f2bf_rh(f0.x); a16[1] = f2bf_rh(f0.y); a16[2] = f2bf_rh(f0.z); a16[3] = f2bf_rh(f0.w);
            a16[4] = f2bf_rh(f1.x); a16[5] = f2bf_rh(f1.y); a16[6] = f2bf_rh(f1.z); a16[7] = f2bf_rh(f1.w);
            a16[8] = f2bf_rh(f2.x); a16[9] = f2bf_rh(f2.y); a16[10] = f2bf_rh(f2.z); a16[11] = f2bf_rh(f2.w);
            a16[12] = f2bf_rh(f3.x); a16[13] = f2bf_rh(f3.y); a16[14] = f2bf_rh(f3.z); a16[15] = f2bf_rh(f3.w);
        }
        {
            float4 g0 = *(const float4*)(pb + k0);
            float4 g1 = *(const float4*)(pb + k0 + 4);
            float4 g2 = *(const float4*)(pb + k0 + 8);
            float4 g3 = *(const float4*)(pb + k0 + 12);
            b16[0] = f2bf_rh(g0.x); b16[1] = f2bf_rh(g0.y); b16[2] = f2bf_rh(g0.z); b16[3] = f2bf_rh(g0.w);
            b16[4] = f2bf_rh(g1.x); b16[5] = f2bf_rh(g1.y); b16[6] = f2bf_rh(g1.z); b16[7] = f2bf_rh(g1.w);
            b16[8] = f2bf_rh(g2.x); b16[9] = f2bf_rh(g2.y); b16[10] = f2bf_rh(g2.z); b16[11] = f2bf_rh(g2.w);
            b16[12] = f2bf_rh(g3.x); b16[13] = f2bf_rh(g3.y); b16[14] = f2bf_rh(g3.z); b16[15] = f2bf_rh(g3.w);
        }
        __syncthreads();
        *(uint4*)&Al[sslot * 8]        = *(uint4*)&a16[0];
        *(uint4*)&Al[(sslot + 16) * 8] = *(uint4*)&a16[8];
        *(uint4*)&Bl[sslot * 8]        = *(uint4*)&b16[0];
        *(uint4*)&Bl[(sslot + 16) * 8] = *(uint4*)&b16[8];
        __syncthreads();

        v8s af[4], bf[4];
#pragma unroll
        for (int ms = 0; ms < 4; ++ms)
            af[ms] = *(const v8s*)&Al[(wm * 4 + ms) * 512 + fbase];
#pragma unroll
        for (int ns = 0; ns < 4; ++ns)
            bf[ns] = *(const v8s*)&Bl[(wn * 4 + ns) * 512 + fbase];
#pragma unroll
        for (int ms = 0; ms < 4; ++ms)
#pragma unroll
            for (int ns = 0; ns < 4; ++ns)
                acc[ms][ns] = __builtin_amdgcn_mfma_f32_16x16x32_bf16(
                    af[ms], bf[ns], acc[ms][ns], 0, 0, 0);
    }

    float bn[4];
#pragma unroll
    for (int ns = 0; ns < 4; ++ns) bn[ns] = bias[n0 + wn * 64 + ns * 16 + c];

#pragma unroll
    for (int ms = 0; ms < 4; ++ms) {
        const int row0 = m0 + wm * 64 + ms * 16 + quad * 4;
#pragma unroll
        for (int ns = 0; ns < 4; ++ns) {
            float v0 = acc[ms][ns][0] + bn[ns];
            float v1 = acc[ms][ns][1] + bn[ns];
            float v2 = acc[ms][ns][2] + bn[ns];
            float v3 = acc[ms][ns][3] + bn[ns];
            if (EPI == 2) {
                float* pc = Cf + (size_t)row0 * Nc + n0 + wn * 64 + ns * 16 + c;
                pc[0] = v0; pc[(size_t)Nc] = v1;
                pc[(size_t)2 * Nc] = v2; pc[(size_t)3 * Nc] = v3;
            } else {
                const int colbase = n0 + wn * 64 + ns * 16;
                const int hh = colbase / 192;
                const int eb = colbase - hh * 192;
                const int bb = row0 >> 11, tok0 = row0 & 2047;
                const int bhh = bb * 16 + hh;
                if (eb >= 128) {
                    ushort4 pk;
                    pk.x = f2bf(v0); pk.y = f2bf(v1); pk.z = f2bf(v2); pk.w = f2bf(v3);
                    *(ushort4*)(VTb + ((size_t)bhh * 64 + (eb - 128) + c) * 2048 + tok0) = pk;
                } else {
                    unsigned short* dst = (eb < 64) ? Kb : Qb;
                    const int e = (eb < 64 ? eb : eb - 64) + c;
                    const size_t base = ((size_t)bhh * 2048 + tok0) * 64 + e;
                    dst[base]       = f2bf(v0);
                    dst[base + 64]  = f2bf(v1);
                    dst[base + 128] = f2bf(v2);
                    dst[base + 192] = f2bf(v3);
                }
            }
        }
    }
}

// ---------------- MFMA flash attention, 128-query blocks ----------------
// grid (8, 64), block 256. Phases: qt = bx, then 15-bx (uniform 34 kt-steps).
// Wave w: 32 queries (2 A-frags), qb = qt*128 + w*32. 64-key tiles in LDS.
// XOR chunk-swizzle: writers place 16B chunk g at position g^(row&3); readers
// fetch chunk quad at quad^(c&3) (row&3 == c&3 for all frag reads).
#define ATTS 72  // row stride in shorts

__global__ __launch_bounds__(256, 2) void attn_mfma(
    const unsigned short* __restrict__ Kbuf,  // [64][2048][64]
    const unsigned short* __restrict__ Qbuf,  // [64][2048][64]
    const unsigned short* __restrict__ VT,    // [64][64][2048]
    unsigned short* __restrict__ sa)          // [8192][1024]
{
    __shared__ __align__(16) unsigned short Ks[64 * ATTS];
    __shared__ __align__(16) unsigned short Vt[64 * ATTS];
    __shared__ __align__(16) unsigned short Ps[4][32 * ATTS];

    const int t = threadIdx.x, w = t >> 6, lane = t & 63;
    const int quad = lane >> 4, c = lane & 15;
    const int bh = blockIdx.y, b = bh >> 4, hh = bh & 15;
    const size_t gbase = (size_t)bh * 2048 * 64;

    const int skey = t >> 2, sdg = t & 3;          // staging: row, 2-chunk group
    const int swk = skey & 3;
    const int p0 = ((2 * sdg) ^ swk) * 8;          // swizzled chunk offsets (shorts)
    const int p1 = ((2 * sdg + 1) ^ swk) * 8;
    const int rs = c & 3;                          // reader swizzle
    const int rc0 = (quad ^ rs) * 8;               // chunk quad   -> offset
    const int rc1 = 32 + rc0;                      // chunk 4+quad -> offset

#pragma unroll 1
    for (int phase = 0; phase < 2; ++phase) {
        const int qt = (phase == 0) ? blockIdx.x : 15 - blockIdx.x;
        const int qb = qt * 128 + w * 32;

        v8s qf[2][2];
#pragma unroll
        for (int qs = 0; qs < 2; ++qs) {
            const size_t qr = gbase + (size_t)(qb + qs * 16 + c) * 64 + quad * 8;
            qf[qs][0] = *(const v8s*)(Qbuf + qr);
            qf[qs][1] = *(const v8s*)(Qbuf + qr + 32);
        }
        v4f oacc[2][4];
        float mrow[2][4], lrow[2][4];
#pragma unroll
        for (int qs = 0; qs < 2; ++qs) {
#pragma unroll
            for (int dn = 0; dn < 4; ++dn) oacc[qs][dn] = (v4f){0.f, 0.f, 0.f, 0.f};
#pragma unroll
            for (int r = 0; r < 4; ++r) { mrow[qs][r] = -1e30f; lrow[qs][r] = 0.f; }
        }

        const int nkt = 2 * qt + 2;
        for (int kt = 0; kt < nkt; ++kt) {
            const int kbase = kt * 64;
            __syncthreads();
            {   // stage 64 keys of K and V^T (swizzled b128 writes, conflict-free)
                const unsigned short* sk = Kbuf + gbase + (size_t)(kbase + skey) * 64 + sdg * 16;
                uint4 k0 = *(const uint4*)sk;
                uint4 k1 = *(const uint4*)(sk + 8);
                *(uint4*)&Ks[skey * ATTS + p0] = k0;
                *(uint4*)&Ks[skey * ATTS + p1] = k1;
                const unsigned short* sv = VT + gbase + (size_t)skey * 2048 + kbase + sdg * 16;
                uint4 u0 = *(const uint4*)sv;
                uint4 u1 = *(const uint4*)(sv + 8);
                *(uint4*)&Vt[skey * ATTS + p0] = u0;
                *(uint4*)&Vt[skey * ATTS + p1] = u1;
            }
            __syncthreads();
            if (kbase > qb + 31) continue;   // this wave done (barriers stay matched)

            // S = Q K^T for both q-subtiles (kf shared)
            v4f s[2][4];
#pragma unroll
            for (int kn = 0; kn < 4; ++kn) {
                const int kr = kn * 16 + c;
                v8s kf0 = *(const v8s*)&Ks[kr * ATTS + rc0];
                v8s kf1 = *(const v8s*)&Ks[kr * ATTS + rc1];
                v4f s0 = (v4f){0.f, 0.f, 0.f, 0.f};
                v4f s1 = (v4f){0.f, 0.f, 0.f, 0.f};
                s0 = __builtin_amdgcn_mfma_f32_16x16x32_bf16(qf[0][0], kf0, s0, 0, 0, 0);
                s0 = __builtin_amdgcn_mfma_f32_16x16x32_bf16(qf[0][1], kf1, s0, 0, 0, 0);
                s1 = __builtin_amdgcn_mfma_f32_16x16x32_bf16(qf[1][0], kf0, s1, 0, 0, 0);
                s1 = __builtin_amdgcn_mfma_f32_16x16x32_bf16(qf[1][1], kf1, s1, 0, 0, 0);
                s[0][kn] = s0; s[1][kn] = s1;
            }

#pragma unroll
            for (int qs = 0; qs < 2; ++qs) {
                const int qsb = qb + qs * 16;
                float sc[4][4];
#pragma unroll
                for (int kn = 0; kn < 4; ++kn)
#pragma unroll
                    for (int r = 0; r < 4; ++r) sc[kn][r] = s[qs][kn][r] * 0.125f;
                if (kbase + 63 > qsb) {      // partial tile: elementwise causal mask
#pragma unroll
                    for (int kn = 0; kn < 4; ++kn)
#pragma unroll
                        for (int r = 0; r < 4; ++r)
                            if (kbase + kn * 16 + c > qsb + quad * 4 + r) sc[kn][r] = -1e30f;
                }
                float tm[4];
#pragma unroll
                for (int r = 0; r < 4; ++r)
                    tm[r] = fmaxf(fmaxf(sc[0][r], sc[1][r]), fmaxf(sc[2][r], sc[3][r]));
#pragma unroll
                for (int d = 1; d < 16; d <<= 1)
#pragma unroll
                    for (int r = 0; r < 4; ++r) tm[r] = fmaxf(tm[r], __shfl_xor(tm[r], d, 16));
                float alpha[4];
#pragma unroll
                for (int r = 0; r < 4; ++r) {
                    float mn = fmaxf(mrow[qs][r], tm[r]);
                    alpha[r] = __expf(mrow[qs][r] - mn);
                    mrow[qs][r] = mn;
                }
                float psum[4] = {0.f, 0.f, 0.f, 0.f};
#pragma unroll
                for (int kn = 0; kn < 4; ++kn)
#pragma unroll
                    for (int r = 0; r < 4; ++r) {
                        float p = __expf(sc[kn][r] - mrow[qs][r]);
                        psum[r] += p;
                        const int pr = qs * 16 + quad * 4 + r;      // pr&3 == r
                        Ps[w][pr * ATTS + (((2 * kn + (c >> 3)) ^ r) * 8) + (c & 7)] = f2bf_rh(p);
                    }
#pragma unroll
                for (int d = 1; d < 16; d <<= 1)
#pragma unroll
                    for (int r = 0; r < 4; ++r) psum[r] += __shfl_xor(psum[r], d, 16);
#pragma unroll
                for (int r = 0; r < 4; ++r) lrow[qs][r] = lrow[qs][r] * alpha[r] + psum[r];
#pragma unroll
                for (int dn = 0; dn < 4; ++dn)
#pragma unroll
                    for (int r = 0; r < 4; ++r) oacc[qs][dn][r] *= alpha[r];
            }

            // O += P V  (vf shared across q-subtiles)
            v8s pa[2][2];
#pragma unroll
            for (int qs = 0; qs < 2; ++qs) {
                const int prr = qs * 16 + c;   // row&3 == c&3 == rs
                pa[qs][0] = *(const v8s*)&Ps[w][prr * ATTS + rc0];
                pa[qs][1] = *(const v8s*)&Ps[w][prr * ATTS + rc1];
            }
#pragma unroll
            for (int dn = 0; dn < 4; ++dn) {
                const int vr = dn * 16 + c;
                v8s vf0 = *(const v8s*)&Vt[vr * ATTS + rc0];
                v8s vf1 = *(const v8s*)&Vt[vr * ATTS + rc1];
                oacc[0][dn] = __builtin_amdgcn_mfma_f32_16x16x32_bf16(pa[0][0], vf0, oacc[0][dn], 0, 0, 0);
                oacc[0][dn] = __builtin_amdgcn_mfma_f32_16x16x32_bf16(pa[0][1], vf1, oacc[0][dn], 0, 0, 0);
                oacc[1][dn] = __builtin_amdgcn_mfma_f32_16x16x32_bf16(pa[1][0], vf0, oacc[1][dn], 0, 0, 0);
                oacc[1][dn] = __builtin_amdgcn_mfma_f32_16x16x32_bf16(pa[1][1], vf1, oacc[1][dn], 0, 0, 0);
            }
        }

        // epilogue: sa[b, qb + qs*16 + quad*4 + r, hh*64 + dn*16 + c]
#pragma unroll
        for (int qs = 0; qs < 2; ++qs) {
            float inv[4];
#pragma unroll
            for (int r = 0; r < 4; ++r) inv[r] = 1.f / lrow[qs][r];
            const size_t obase =
                ((size_t)(b * 2048 + qb + qs * 16 + quad * 4)) * DMODEL + hh * 64;
#pragma unroll
            for (int dn = 0; dn < 4; ++dn)
#pragma unroll
                for (int r = 0; r < 4; ++r)
                    sa[obase + (size_t)r * DMODEL + dn * 16 + c] = f2bf(oacc[qs][dn][r] * inv[r]);
        }
    }
}

extern "C" void kernel_launch(void* const* d_in, const int* in_sizes, int n_in,
                              void* d_out, int out_size, void* d_ws, size_t ws_size,
                              hipStream_t stream) {
    const float* x     = (const float*)d_in[0];  // [4,2048,1024]
    const float* Wkqv  = (const float*)d_in[1];  // [16,192,1024]
    const float* bkqv  = (const float*)d_in[2];  // [16,192]
    const float* Wproj = (const float*)d_in[3];  // [1024,1024]
    const float* bproj = (const float*)d_in[4];  // [1024]
    float* out = (float*)d_out;                  // [4,2048,1024] fp32

    unsigned short* Kb = (unsigned short*)d_ws;        // [64][2048][64]
    unsigned short* Qb = Kb + (size_t)8388608;         // [64][2048][64]
    unsigned short* VT = Qb + (size_t)8388608;         // [64][64][2048]
    unsigned short* sa = VT + (size_t)8388608;         // [8192][1024]

    const bool fast = ws_size >= 75497472ull;          // 72 MiB
    if (fast) {
        unsigned short* xb  = sa;                      // overlap: xb dead before attn
        unsigned short* wkb = (unsigned short*)d_ws + (size_t)33554432;
        unsigned short* wpb = wkb + (size_t)3145728;
        cvt_bf16<<<12288, 256, 0, stream>>>(x, Wkqv, Wproj, xb, wkb, wpb);
        gemm_lds<1><<<dim3(24, 64), 256, 0, stream>>>(
            xb, wkb, bkqv, nullptr, Kb, Qb, VT, 8192, 3072, 1024);
        attn_mfma<<<dim3(8, 64), 256, 0, stream>>>(Kb, Qb, VT, sa);
        gemm_lds<2><<<dim3(8, 64), 256, 0, stream>>>(
            sa, wpb, bproj, out, nullptr, nullptr, nullptr, 8192, 1024, 1024);
    } else {
        gemm_mfma<false, 1><<<dim3(24, 64), 256, 0, stream>>>(
            x, Wkqv, bkqv, nullptr, Kb, Qb, VT, 8192, 3072, 1024);
        attn_mfma<<<dim3(8, 64), 256, 0, stream>>>(Kb, Qb, VT, sa);
        gemm_mfma<true, 2><<<dim3(8, 64), 256, 0, stream>>>(
            sa, Wproj, bproj, out, nullptr, nullptr, nullptr, 8192, 1024, 1024);
    }
}

// Round 7
// 334.054 us; speedup vs baseline: 19.5255x; 1.0450x over previous
//
#include <hip/hip_runtime.h>
#include <hip/hip_bf16.h>

// CausalSelfAttention: B=4, N=2048, D=1024, H=16, HD=64. fp32 in / fp32 out.
// R7: constant-m softmax (P = exp2(s) raw; |s2| <= 46 hard bound -> no max tracking,
//     no rescaling, l via ones-MFMA), barrier-free attn (K/V frags direct from
//     global/L2, Ps per-wave LDS), wave = 64 queries; 0.125*log2e folded into Qb;
//     class-major weight permute in cvt; gemm launch_bounds(256,3).
// ws: Kb/Qb/VT/sa 4x16.78MB = 64MiB; fast path adds wkb+wpb -> 72MiB; xb overlaps sa.

#define NSEQ 2048
#define NHEAD 16
#define DMODEL 1024
#define SCALE2 0.18033688011112042f  // 0.125 * log2(e)

typedef __attribute__((ext_vector_type(8))) short v8s;  // 8 bf16 = 4 VGPRs
typedef __attribute__((ext_vector_type(4))) float v4f;  // MFMA acc

__device__ __forceinline__ float bf2f(unsigned short u) {
    union { unsigned int i; float f; } v;
    v.i = ((unsigned int)u) << 16;
    return v.f;
}
__device__ __forceinline__ unsigned short f2bf(float f) {  // RNE
    unsigned int x = __float_as_uint(f);
    return (unsigned short)((x + 0x7fffu + ((x >> 16) & 1u)) >> 16);
}
__device__ __forceinline__ unsigned short f2bf_rh(float f) {  // round-half-up
    return (unsigned short)((__float_as_uint(f) + 0x8000u) >> 16);
}
__device__ __forceinline__ float fast_exp2(float x) {
#if __has_builtin(__builtin_amdgcn_exp2f)
    return __builtin_amdgcn_exp2f(x);
#else
    return __expf(x * 0.69314718056f);
#endif
}
__device__ __forceinline__ void gld_lds16(const unsigned short* g, unsigned short* l) {
    __builtin_amdgcn_global_load_lds(
        (const __attribute__((address_space(1))) void*)g,
        (__attribute__((address_space(3))) void*)l, 16, 0, 0);
}

// ---------------- cvt: fp32 -> bf16 for x, Wkqv (class-major permute), Wproj -------
// Wkqv in rows h*192 + cls*64 + e -> wkb rows cls*1024 + h*64 + e.
__global__ __launch_bounds__(256) void cvt_bf16(
    const float* __restrict__ x, const float* __restrict__ wk, const float* __restrict__ wp,
    unsigned short* __restrict__ xb, unsigned short* __restrict__ wkb,
    unsigned short* __restrict__ wpb)
{
    const int i = blockIdx.x * 256 + threadIdx.x;   // quad index, 3145728 total
    const float* s; unsigned short* d; int o;
    if (i < 2097152)      { s = x;  d = xb;  o = i; }
    else if (i < 2883584) {
        s = wk; d = wkb;
        const int oi  = i - 2097152;          // 0..786431
        const int row = oi >> 8, cq = oi & 255;
        const int h   = row / 192;
        const int rem = row - h * 192;
        const int cls = rem >> 6, e = rem & 63;
        float4 f = ((const float4*)s)[oi];
        ushort4 u;
        u.x = f2bf(f.x); u.y = f2bf(f.y); u.z = f2bf(f.z); u.w = f2bf(f.w);
        ((ushort4*)d)[(((cls << 10) + (h << 6) + e) << 8) + cq] = u;
        return;
    }
    else                  { s = wp; d = wpb; o = i - 2883584; }
    float4 f = ((const float4*)s)[o];
    ushort4 u;
    u.x = f2bf(f.x); u.y = f2bf(f.y); u.z = f2bf(f.z); u.w = f2bf(f.w);
    ((ushort4*)d)[o] = u;
}

// ---------------- fast MFMA GEMM: bf16 A/B, global_load_lds staging ----------------
// C[M,Nc] = A[M,K] @ B[Nc,K]^T + bias. 128x128 tile, 256 thr, BK=32.
// EPI=1: B is class-major-permuted kqv weights; split-write Kb/Qb(scaled)/VT.
// EPI=2: plain fp32 C.
template <int EPI>
__global__ __launch_bounds__(256, 3) void gemm_lds(
    const unsigned short* __restrict__ A, const unsigned short* __restrict__ B,
    const float* __restrict__ bias,
    float* __restrict__ Cf,
    unsigned short* __restrict__ Kb, unsigned short* __restrict__ Qb,
    unsigned short* __restrict__ VTb,
    int M, int Nc, int K)
{
    __shared__ __align__(16) unsigned short Al[512 * 8];
    __shared__ __align__(16) unsigned short Bl[512 * 8];

    const int t = threadIdx.x, wave = t >> 6, lane = t & 63;
    const int wm = wave >> 1, wn = wave & 1;
    const int m0 = blockIdx.y * 128, n0 = blockIdx.x * 128;
    const int quad = lane >> 4, c = lane & 15;

    const int g0 = wave * 2, g1 = wave * 2 + 1;
    const int r15 = lane & 15, kg = (lane >> 4) & 3;
    const unsigned short* sA0 = A + (size_t)(m0 + g0 * 16 + r15) * K + kg * 8;
    const unsigned short* sA1 = A + (size_t)(m0 + g1 * 16 + r15) * K + kg * 8;
    const unsigned short* sB0 = B + (size_t)(n0 + g0 * 16 + r15) * K + kg * 8;
    const unsigned short* sB1 = B + (size_t)(n0 + g1 * 16 + r15) * K + kg * 8;
    unsigned short* dA0 = &Al[g0 * 512];
    unsigned short* dA1 = &Al[g1 * 512];
    unsigned short* dB0 = &Bl[g0 * 512];
    unsigned short* dB1 = &Bl[g1 * 512];

    v4f acc[4][4];
#pragma unroll
    for (int i = 0; i < 4; ++i)
#pragma unroll
        for (int j = 0; j < 4; ++j) acc[i][j] = (v4f){0.f, 0.f, 0.f, 0.f};

    const int fbase = (quad * 16 + c) * 8;

    for (int k0 = 0; k0 < K; k0 += 32) {
        __syncthreads();
        gld_lds16(sA0 + k0, dA0);
        gld_lds16(sA1 + k0, dA1);
        gld_lds16(sB0 + k0, dB0);
        gld_lds16(sB1 + k0, dB1);
        __syncthreads();

        v8s af[4], bf[4];
#pragma unroll
        for (int ms = 0; ms < 4; ++ms)
            af[ms] = *(const v8s*)&Al[(wm * 4 + ms) * 512 + fbase];
#pragma unroll
        for (int ns = 0; ns < 4; ++ns)
            bf[ns] = *(const v8s*)&Bl[(wn * 4 + ns) * 512 + fbase];
#pragma unroll
        for (int ms = 0; ms < 4; ++ms)
#pragma unroll
            for (int ns = 0; ns < 4; ++ns)
                acc[ms][ns] = __builtin_amdgcn_mfma_f32_16x16x32_bf16(
                    af[ms], bf[ns], acc[ms][ns], 0, 0, 0);
    }

#pragma unroll
    for (int ms = 0; ms < 4; ++ms) {
        const int row0 = m0 + wm * 64 + ms * 16 + quad * 4;
#pragma unroll
        for (int ns = 0; ns < 4; ++ns) {
            const int colbase = n0 + wn * 64 + ns * 16;   // block-uniform, 16-aligned
            float bn, scl = 1.f;
            if (EPI == 2) {
                bn = bias[colbase + c];
            } else {
                const int cls = colbase >> 10;
                const int wi  = colbase & 1023;
                const int h   = wi >> 6, e0 = wi & 63;
                bn = bias[h * 192 + cls * 64 + e0 + c];
                if (cls == 1) scl = SCALE2;
            }
            float v0 = (acc[ms][ns][0] + bn) * scl;
            float v1 = (acc[ms][ns][1] + bn) * scl;
            float v2 = (acc[ms][ns][2] + bn) * scl;
            float v3 = (acc[ms][ns][3] + bn) * scl;
            if (EPI == 2) {
                float* pc = Cf + (size_t)row0 * Nc + colbase + c;
                pc[0] = v0; pc[(size_t)Nc] = v1;
                pc[(size_t)2 * Nc] = v2; pc[(size_t)3 * Nc] = v3;
            } else {
                const int cls = colbase >> 10;
                const int wi  = colbase & 1023;
                const int h   = wi >> 6, e = (wi & 63) + c;
                const int bb  = row0 >> 11, tok0 = row0 & 2047;
                const int bhh = bb * 16 + h;
                if (cls == 2) {            // V -> transposed [bh][dim][tok]
                    ushort4 pk;
                    pk.x = f2bf(v0); pk.y = f2bf(v1); pk.z = f2bf(v2); pk.w = f2bf(v3);
                    *(ushort4*)(VTb + ((size_t)bhh * 64 + e) * 2048 + tok0) = pk;
                } else {                   // K or Q -> [bh][tok][dim]
                    unsigned short* dst = (cls == 0) ? Kb : Qb;
                    const size_t base = ((size_t)bhh * 2048 + tok0) * 64 + e;
                    dst[base]       = f2bf(v0);
                    dst[base + 64]  = f2bf(v1);
                    dst[base + 128] = f2bf(v2);
                    dst[base + 192] = f2bf(v3);
                }
            }
        }
    }
}

// ---------------- fallback GEMM (fp32 sources, VGPR-roundtrip staging) -------------
// EPI=1 uses ORIGINAL (unpermuted) Wkqv col mapping h*192+e; scales Q by SCALE2.
template <bool A_BF16, int EPI>
__global__ __launch_bounds__(256) void gemm_mfma(
    const void* __restrict__ Av, const float* __restrict__ B,
    const float* __restrict__ bias,
    float* __restrict__ Cf,
    unsigned short* __restrict__ Kb, unsigned short* __restrict__ Qb,
    unsigned short* __restrict__ VTb,
    int M, int Nc, int K)
{
    __shared__ __align__(16) unsigned short Al[512 * 8];
    __shared__ __align__(16) unsigned short Bl[512 * 8];

    const int t = threadIdx.x;
    const int wave = t >> 6, lane = t & 63;
    const int wm = wave >> 1, wn = wave & 1;
    const int m0 = blockIdx.y * 128, n0 = blockIdx.x * 128;
    const int quad = lane >> 4, c = lane & 15;

    const int srow = t >> 1, skh = t & 1;
    const int sslot = (srow >> 4) * 64 + (skh * 2) * 16 + (srow & 15);

    v4f acc[4][4];
#pragma unroll
    for (int i = 0; i < 4; ++i)
#pragma unroll
        for (int j = 0; j < 4; ++j) acc[i][j] = (v4f){0.f, 0.f, 0.f, 0.f};

    const unsigned short* pa_u = (const unsigned short*)Av + (size_t)(m0 + srow) * K + skh * 16;
    const float*          pa_f = (const float*)Av          + (size_t)(m0 + srow) * K + skh * 16;
    const float*          pb   = B                          + (size_t)(n0 + srow) * K + skh * 16;

    const int fbase = (quad * 16 + c) * 8;

    for (int k0 = 0; k0 < K; k0 += 32) {
        unsigned short a16[16], b16[16];
        if (A_BF16) {
            uint4 r0 = *(const uint4*)(pa_u + k0);
            uint4 r1 = *(const uint4*)(pa_u + k0 + 8);
            *(uint4*)&a16[0] = r0; *(uint4*)&a16[8] = r1;
        } else {
            float4 f0 = *(const float4*)(pa_f + k0);
            float4 f1 = *(const float4*)(pa_f + k0 + 4);
            float4 f2 = *(const float4*)(pa_f + k0 + 8);
            float4 f3 = *(const float4*)(pa_f + k0 + 12);
            a16[0] = f2bf_rh(f0.x); a16[1] = f2bf_rh(f0.y); a16[2] = f2bf_rh(f0.z); a16[3] = f2bf_rh(f0.w);
            a16[4] = f2bf_rh(f1.x); a16[5] = f2bf_rh(f1.y); a16[6] = f2bf_rh(f1.z); a16[7] = f2bf_rh(f1.w);
            a16[8] = f2bf_rh(f2.x); a16[9] = f2bf_rh(f2.y); a16[10] = f2bf_rh(f2.z); a16[11] = f2bf_rh(f2.w);
            a16[12] = f2bf_rh(f3.x); a16[13] = f2bf_rh(f3.y); a16[14] = f2bf_rh(f3.z); a16[15] = f2bf_rh(f3.w);
        }
        {
            float4 g0 = *(const float4*)(pb + k0);
            float4 g1 = *(const float4*)(pb + k0 + 4);
            float4 g2 = *(const float4*)(pb + k0 + 8);
            float4 g3 = *(const float4*)(pb + k0 + 12);
            b16[0] = f2bf_rh(g0.x); b16[1] = f2bf_rh(g0.y); b16[2] = f2bf_rh(g0.z); b16[3] = f2bf_rh(g0.w);
            b16[4] = f2bf_rh(g1.x); b16[5] = f2bf_rh(g1.y); b16[6] = f2bf_rh(g1.z); b16[7] = f2bf_rh(g1.w);
            b16[8] = f2bf_rh(g2.x); b16[9] = f2bf_rh(g2.y); b16[10] = f2bf_rh(g2.z); b16[11] = f2bf_rh(g2.w);
            b16[12] = f2bf_rh(g3.x); b16[13] = f2bf_rh(g3.y); b16[14] = f2bf_rh(g3.z); b16[15] = f2bf_rh(g3.w);
        }
        __syncthreads();
        *(uint4*)&Al[sslot * 8]        = *(uint4*)&a16[0];
        *(uint4*)&Al[(sslot + 16) * 8] = *(uint4*)&a16[8];
        *(uint4*)&Bl[sslot * 8]        = *(uint4*)&b16[0];
        *(uint4*)&Bl[(sslot + 16) * 8] = *(uint4*)&b16[8];
        __syncthreads();

        v8s af[4], bf[4];
#pragma unroll
        for (int ms = 0; ms < 4; ++ms)
            af[ms] = *(const v8s*)&Al[(wm * 4 + ms) * 512 + fbase];
#pragma unroll
        for (int ns = 0; ns < 4; ++ns)
            bf[ns] = *(const v8s*)&Bl[(wn * 4 + ns) * 512 + fbase];
#pragma unroll
        for (int ms = 0; ms < 4; ++ms)
#pragma unroll
            for (int ns = 0; ns < 4; ++ns)
                acc[ms][ns] = __builtin_amdgcn_mfma_f32_16x16x32_bf16(
                    af[ms], bf[ns], acc[ms][ns], 0, 0, 0);
    }

#pragma unroll
    for (int ms = 0; ms < 4; ++ms) {
        const int row0 = m0 + wm * 64 + ms * 16 + quad * 4;
#pragma unroll
        for (int ns = 0; ns < 4; ++ns) {
            const int colbase = n0 + wn * 64 + ns * 16;
            float bn = (EPI == 2) ? bias[colbase + c] : bias[colbase + c];
            float v0 = acc[ms][ns][0] + bn;
            float v1 = acc[ms][ns][1] + bn;
            float v2 = acc[ms][ns][2] + bn;
            float v3 = acc[ms][ns][3] + bn;
            if (EPI == 2) {
                float* pc = Cf + (size_t)row0 * Nc + colbase + c;
                pc[0] = v0; pc[(size_t)Nc] = v1;
                pc[(size_t)2 * Nc] = v2; pc[(size_t)3 * Nc] = v3;
            } else {
                const int hh = colbase / 192;
                const int eb = colbase - hh * 192;
                const int bb = row0 >> 11, tok0 = row0 & 2047;
                const int bhh = bb * 16 + hh;
                if (eb >= 128) {
                    ushort4 pk;
                    pk.x = f2bf(v0); pk.y = f2bf(v1); pk.z = f2bf(v2); pk.w = f2bf(v3);
                    *(ushort4*)(VTb + ((size_t)bhh * 64 + (eb - 128) + c) * 2048 + tok0) = pk;
                } else {
                    const bool isq = (eb >= 64);
                    const float s = isq ? SCALE2 : 1.f;
                    unsigned short* dst = isq ? Qb : Kb;
                    const int e = (isq ? eb - 64 : eb) + c;
                    const size_t base = ((size_t)bhh * 2048 + tok0) * 64 + e;
                    dst[base]       = f2bf(v0 * s);
                    dst[base + 64]  = f2bf(v1 * s);
                    dst[base + 128] = f2bf(v2 * s);
                    dst[base + 192] = f2bf(v3 * s);
                }
            }
        }
    }
}

// ---------------- barrier-free MFMA flash attention, constant-m softmax -----------
// grid 512 x 256thr. bh = blockIdx&63 (XCD-grouped), bq = blockIdx>>6 (0..7).
// Wave w handles 64 queries of qt in {bq, 15-bq, 16+bq, 31-bq} (uniform 66 kt/block).
// Q pre-scaled by 0.125*log2e; P = exp2(s) raw (|s|<=46 hard bound); l via ones-MFMA.
// K/V fragments read directly from global (L2); only Ps (per-wave) uses LDS.
#define ATTS 72

__global__ __launch_bounds__(256, 2) void attn_mfma(
    const unsigned short* __restrict__ Kbuf,  // [64][2048][64]
    const unsigned short* __restrict__ Qbuf,  // [64][2048][64] (scaled)
    const unsigned short* __restrict__ VT,    // [64][64][2048]
    unsigned short* __restrict__ sa)          // [8192][1024]
{
    __shared__ __align__(16) unsigned short Ps[4][64 * ATTS];

    const int t = threadIdx.x, w = t >> 6, lane = t & 63;
    const int quad = lane >> 4, c = lane & 15;
    const int bh = blockIdx.x & 63, bq = blockIdx.x >> 6;
    const int b = bh >> 4, hh = bh & 15;
    const int qt = (w == 0) ? bq : (w == 1) ? (15 - bq) : (w == 2) ? (16 + bq) : (31 - bq);
    const int qw = qt * 64;
    const size_t gbase = (size_t)bh * (2048 * 64);

    const int rs  = c & 3;
    const int rc0 = (quad ^ rs) * 8, rc1 = 32 + rc0;
    unsigned short* PsW = &Ps[w][0];

    v8s qf[4][2];
#pragma unroll
    for (int qs = 0; qs < 4; ++qs) {
        const unsigned short* qp = Qbuf + gbase + (size_t)(qw + qs * 16 + c) * 64 + quad * 8;
        qf[qs][0] = *(const v8s*)qp;
        qf[qs][1] = *(const v8s*)(qp + 32);
    }
    v4f oacc[4][4], lacc[4];
#pragma unroll
    for (int qs = 0; qs < 4; ++qs) {
        lacc[qs] = (v4f){0.f, 0.f, 0.f, 0.f};
#pragma unroll
        for (int dn = 0; dn < 4; ++dn) oacc[qs][dn] = (v4f){0.f, 0.f, 0.f, 0.f};
    }
    const short oneb = (short)0x3F80;  // bf16 1.0
    const v8s ones = {oneb, oneb, oneb, oneb, oneb, oneb, oneb, oneb};

    const int nkt = qt + 1;
    for (int kt = 0; kt < nkt; ++kt) {
        const int kbase = kt * 64;
        const bool diag = (kt == nkt - 1);   // wave-uniform; kbase == qw on this kt
        // ---- S = Q K^T, P = exp2(S) streamed straight into Ps (A-layout via swizzle)
#pragma unroll
        for (int kn = 0; kn < 4; ++kn) {
            const unsigned short* kp =
                Kbuf + gbase + (size_t)(kbase + kn * 16 + c) * 64 + quad * 8;
            v8s kf0 = *(const v8s*)kp;
            v8s kf1 = *(const v8s*)(kp + 32);
#pragma unroll
            for (int qs = 0; qs < 4; ++qs) {
                v4f s = (v4f){0.f, 0.f, 0.f, 0.f};
                s = __builtin_amdgcn_mfma_f32_16x16x32_bf16(qf[qs][0], kf0, s, 0, 0, 0);
                s = __builtin_amdgcn_mfma_f32_16x16x32_bf16(qf[qs][1], kf1, s, 0, 0, 0);
                if (diag) {
#pragma unroll
                    for (int r = 0; r < 4; ++r)
                        if (kn * 16 + c > qs * 16 + quad * 4 + r) s[r] = -1e30f;
                }
#pragma unroll
                for (int r = 0; r < 4; ++r) {
                    const float p = fast_exp2(s[r]);
                    PsW[(qs * 16 + quad * 4 + r) * ATTS +
                        (((2 * kn + (c >> 3)) ^ r) * 8) + (c & 7)] = f2bf_rh(p);
                }
            }
        }
        // ---- P fragments (A-layout), then O += P V and l += P @ ones
        v8s pa[4][2];
#pragma unroll
        for (int qs = 0; qs < 4; ++qs) {
            pa[qs][0] = *(const v8s*)&PsW[(qs * 16 + c) * ATTS + rc0];
            pa[qs][1] = *(const v8s*)&PsW[(qs * 16 + c) * ATTS + rc1];
        }
#pragma unroll
        for (int dn = 0; dn < 4; ++dn) {
            const unsigned short* vp =
                VT + gbase + (size_t)(dn * 16 + c) * 2048 + kbase + quad * 8;
            v8s vf0 = *(const v8s*)vp;
            v8s vf1 = *(const v8s*)(vp + 32);
#pragma unroll
            for (int qs = 0; qs < 4; ++qs) {
                oacc[qs][dn] = __builtin_amdgcn_mfma_f32_16x16x32_bf16(pa[qs][0], vf0, oacc[qs][dn], 0, 0, 0);
                oacc[qs][dn] = __builtin_amdgcn_mfma_f32_16x16x32_bf16(pa[qs][1], vf1, oacc[qs][dn], 0, 0, 0);
            }
        }
#pragma unroll
        for (int qs = 0; qs < 4; ++qs) {
            lacc[qs] = __builtin_amdgcn_mfma_f32_16x16x32_bf16(pa[qs][0], ones, lacc[qs], 0, 0, 0);
            lacc[qs] = __builtin_amdgcn_mfma_f32_16x16x32_bf16(pa[qs][1], ones, lacc[qs], 0, 0, 0);
        }
    }

    // epilogue: sa[b, qw + qs*16 + quad*4 + r, hh*64 + dn*16 + c]
#pragma unroll
    for (int qs = 0; qs < 4; ++qs) {
        float inv[4];
#pragma unroll
        for (int r = 0; r < 4; ++r) inv[r] = 1.f / lacc[qs][r];
        const size_t obase =
            ((size_t)(b * 2048 + qw + qs * 16 + quad * 4)) * DMODEL + hh * 64;
#pragma unroll
        for (int dn = 0; dn < 4; ++dn)
#pragma unroll
            for (int r = 0; r < 4; ++r)
                sa[obase + (size_t)r * DMODEL + dn * 16 + c] = f2bf(oacc[qs][dn][r] * inv[r]);
    }
}

extern "C" void kernel_launch(void* const* d_in, const int* in_sizes, int n_in,
                              void* d_out, int out_size, void* d_ws, size_t ws_size,
                              hipStream_t stream) {
    const float* x     = (const float*)d_in[0];
    const float* Wkqv  = (const float*)d_in[1];
    const float* bkqv  = (const float*)d_in[2];
    const float* Wproj = (const float*)d_in[3];
    const float* bproj = (const float*)d_in[4];
    float* out = (float*)d_out;

    unsigned short* Kb = (unsigned short*)d_ws;        // [64][2048][64]
    unsigned short* Qb = Kb + (size_t)8388608;         // [64][2048][64]
    unsigned short* VT = Qb + (size_t)8388608;         // [64][64][2048]
    unsigned short* sa = VT + (size_t)8388608;         // [8192][1024]

    const bool fast = ws_size >= 75497472ull;          // 72 MiB
    if (fast) {
        unsigned short* xb  = sa;                      // xb dead before attn writes sa
        unsigned short* wkb = (unsigned short*)d_ws + (size_t)33554432;
        unsigned short* wpb = wkb + (size_t)3145728;
        cvt_bf16<<<12288, 256, 0, stream>>>(x, Wkqv, Wproj, xb, wkb, wpb);
        gemm_lds<1><<<dim3(24, 64), 256, 0, stream>>>(
            xb, wkb, bkqv, nullptr, Kb, Qb, VT, 8192, 3072, 1024);
        attn_mfma<<<512, 256, 0, stream>>>(Kb, Qb, VT, sa);
        gemm_lds<2><<<dim3(8, 64), 256, 0, stream>>>(
            sa, wpb, bproj, out, nullptr, nullptr, nullptr, 8192, 1024, 1024);
    } else {
        gemm_mfma<false, 1><<<dim3(24, 64), 256, 0, stream>>>(
            x, Wkqv, bkqv, nullptr, Kb, Qb, VT, 8192, 3072, 1024);
        attn_mfma<<<512, 256, 0, stream>>>(Kb, Qb, VT, sa);
        gemm_mfma<true, 2><<<dim3(8, 64), 256, 0, stream>>>(
            sa, Wproj, bproj, out, nullptr, nullptr, nullptr, 8192, 1024, 1024);
    }
}